// Round 24
// baseline (99.430 us; speedup 1.0000x reference)
//
#include <hip/hip_runtime.h>
#include <stdint.h>

// Problem constants
#define B_     2
#define NQ     2048
#define NKV    2048
#define D_     512
#define H_     8
#define HD     64
#define MROWS  4096   // B_*NQ == B_*NKV

typedef unsigned short u16;
typedef __attribute__((ext_vector_type(4))) unsigned short u16x4;
typedef __attribute__((ext_vector_type(8))) unsigned short u16x8;
typedef __attribute__((ext_vector_type(8))) __bf16 bf16x8;
typedef __attribute__((ext_vector_type(4))) float f32x4;

__device__ __forceinline__ u16 f2bf(float f) {
  union { float f; unsigned int u; } v; v.f = f;
  unsigned int u = v.u;
  unsigned int r = (u + 0x7FFFu + ((u >> 16) & 1u)) >> 16;  // RNE
  return (u16)r;
}
__device__ __forceinline__ float bf2f(u16 b) {
  union { unsigned int u; float f; } v; v.u = ((unsigned int)b) << 16;
  return v.f;
}
__device__ __forceinline__ unsigned cvtpk(float a, float b) {  // low=bf(a), high=bf(b)
  unsigned r;
  asm("v_cvt_pk_bf16_f32 %0, %1, %2" : "=v"(r) : "v"(a), "v"(b));
  return r;
}
// Raw v_exp_f32 (2^x), single instruction (verified r21: halves VALUBusy).
__device__ __forceinline__ float exp2fast(float x) {
  return __builtin_amdgcn_exp2f(x);
}

__device__ __forceinline__ f32x4 mfma16(u16x8 a, u16x8 b, f32x4 c) {
  return __builtin_amdgcn_mfma_f32_16x16x32_bf16(
      __builtin_bit_cast(bf16x8, a), __builtin_bit_cast(bf16x8, b), c, 0, 0, 0);
}

// log2(e)/sqrt(HD): folded into the Q projection so exp2 applies directly.
#define QSCL 0.18033688011112042f

// ---------------------------------------------------------------------------
// Kernel 1: fused input prep (round-16/17 verified verbatim).
// ---------------------------------------------------------------------------
__global__ __launch_bounds__(256) void prep_kernel(
    const float* __restrict__ q, const float* __restrict__ kv,
    const float* __restrict__ Wq, const float* __restrict__ Wk,
    const float* __restrict__ Wv,
    u16* __restrict__ qb, u16* __restrict__ kvb,
    u16* __restrict__ wqt, u16* __restrict__ wkt, u16* __restrict__ wvt) {
  __shared__ float tile[32][33];
  int bx = blockIdx.x;
  if (bx < 2048) {
    int i = bx * 256 + threadIdx.x;   // 524288 exact
    float4 a = ((const float4*)q)[i];
    float4 b = ((const float4*)kv)[i];
    u16x4 ua = { f2bf(a.x), f2bf(a.y), f2bf(a.z), f2bf(a.w) };
    u16x4 ub = { f2bf(b.x), f2bf(b.y), f2bf(b.z), f2bf(b.w) };
    ((u16x4*)qb)[i]  = ua;
    ((u16x4*)kvb)[i] = ub;
  } else {
    int t = bx - 2048;                 // 0..767
    int which = t >> 8;
    t &= 255;
    int tr = t >> 4, tc = t & 15;      // tile row (k), tile col (n) in W
    const float* W = (which == 0) ? Wq : (which == 1) ? Wk : Wv;
    u16* WT = (which == 0) ? wqt : (which == 1) ? wkt : wvt;

    int tx = threadIdx.x & 31, ty = threadIdx.x >> 5;  // ty 0..7
#pragma unroll
    for (int i = 0; i < 4; ++i)
      tile[ty + 8 * i][tx] = W[(size_t)(tr * 32 + ty + 8 * i) * D_ + tc * 32 + tx];
    __syncthreads();
#pragma unroll
    for (int i = 0; i < 4; ++i)
      WT[(size_t)(tc * 32 + ty + 8 * i) * D_ + tr * 32 + tx] =
          f2bf(tile[tx][ty + 8 * i]);
  }
}

// ---------------------------------------------------------------------------
// Kernel 2: fused QKV GEMM (round-16 verified verbatim — best measured).
// ---------------------------------------------------------------------------
__global__ __launch_bounds__(64) void gemm_qkv(
    const u16* __restrict__ qb, const u16* __restrict__ kvb,
    const u16* __restrict__ wqt, const u16* __restrict__ wkt,
    const u16* __restrict__ wvt,
    const float* __restrict__ bq, const float* __restrict__ bk,
    const float* __restrict__ bv,
    u16* __restrict__ Qp, u16* __restrict__ Kp, u16* __restrict__ VpT) {
  __shared__ __align__(16) u16 tile[64][72];   // +8 pad -> 16B-aligned rows

  int lane = threadIdx.x;
  int cl = lane & 15, g = lane >> 4;
  int y = blockIdx.y;
  int which = y >> 3;
  int col0 = (y & 7) * 64;
  int row0 = blockIdx.x * 64;

  const u16* A   = (which == 0) ? qb : kvb;
  const u16* WT  = (which == 0) ? wqt : (which == 1) ? wkt : wvt;
  const float* bias = (which == 0) ? bq : (which == 1) ? bk : bv;
  u16* Out = (which == 0) ? Qp : (which == 1) ? Kp : VpT;
  float oscale = (which == 0) ? QSCL : 1.0f;

  const u16* Abase = A  + (size_t)(row0 + cl) * D_ + g * 8;
  const u16* Bbase = WT + (size_t)(col0 + cl) * D_ + g * 8;

  f32x4 acc[4][4] = {};
  u16x8 afA[4], bfA[4], afB[4], bfB[4];
#pragma unroll
  for (int i = 0; i < 4; ++i) afA[i] = *(const u16x8*)(Abase + (size_t)i * 16 * D_);
#pragma unroll
  for (int j = 0; j < 4; ++j) bfA[j] = *(const u16x8*)(Bbase + (size_t)j * 16 * D_);

#pragma unroll
  for (int kk = 0; kk < 16; ++kk) {
    const u16x8* ca = (kk & 1) ? afB : afA;
    const u16x8* cw = (kk & 1) ? bfB : bfA;
    u16x8* na = (kk & 1) ? afA : afB;
    u16x8* nw = (kk & 1) ? bfA : bfB;
    if (kk < 15) {                        // static guard (unrolled) — no spill
      int k0 = kk * 32 + 32;
#pragma unroll
      for (int i = 0; i < 4; ++i) na[i] = *(const u16x8*)(Abase + (size_t)i * 16 * D_ + k0);
#pragma unroll
      for (int j = 0; j < 4; ++j) nw[j] = *(const u16x8*)(Bbase + (size_t)j * 16 * D_ + k0);
    }
    __builtin_amdgcn_s_setprio(1);
#pragma unroll
    for (int i = 0; i < 4; ++i)
#pragma unroll
      for (int j = 0; j < 4; ++j)
        acc[i][j] = mfma16(ca[i], cw[j], acc[i][j]);
    __builtin_amdgcn_s_setprio(0);
  }

  // Epilogue: bias + scale -> LDS tile -> coalesced 16B stores.
#pragma unroll
  for (int j = 0; j < 4; ++j) {
    float bv2 = bias[col0 + j * 16 + cl];
#pragma unroll
    for (int i = 0; i < 4; ++i)
#pragma unroll
      for (int r = 0; r < 4; ++r) {
        u16 val = f2bf((acc[i][j][r] + bv2) * oscale);
        int rr = i * 16 + g * 4 + r, cc = j * 16 + cl;
        if (which != 2) tile[rr][cc] = val;
        else            tile[cc][rr] = val;
      }
  }
  u16* dst;
  if (which != 2) {
    dst = Out + (size_t)(row0 + lane) * D_ + col0;
  } else {
    int b_ = row0 >> 11, key0 = row0 & (NKV - 1);
    dst = Out + (size_t)b_ * (D_ * NKV) + (size_t)(col0 + lane) * NKV + key0;
  }
#pragma unroll
  for (int c8 = 0; c8 < 8; ++c8) {
    uint4 v = *(const uint4*)&tile[lane][c8 * 8];
    *(uint4*)(dst + c8 * 8) = v;
  }
}

// ---------------------------------------------------------------------------
// Kernel 3: flash attention, NO KV SPLIT (each block covers all 2048 keys
// for its 64 q-rows; NT=32, grid 512). r21/r23-verified body otherwise:
// 1 wave/block, swapped QK^T, fixed-max exp2fast softmax, pointer-carried
// fragments, XCD-affinity grid. Output is NORMALIZED in-register (1/lsum)
// and stored directly — no ml array, no combine merge.
// ---------------------------------------------------------------------------
__global__ __launch_bounds__(64, 2) void attn_kernel(
    const u16* __restrict__ Q, const u16* __restrict__ K,
    const u16* __restrict__ VpT, u16* __restrict__ octx) {
  __shared__ union __align__(16) {
    u16 p[64][66];       // P: [q_local][key], stride 132B (round-2 pattern)
    unsigned t[64][33];  // epilogue O transpose (same 132B row stride)
  } sm;

  int lane = threadIdx.x;              // one wave
  int cl = lane & 15, g = lane >> 4;

  // XCD-affinity decode: 512 blocks; per bh: 32 q-tiles. Bijective.
  int lin = blockIdx.x;                // 0..511
  int xcd = lin & 7, k_ = lin >> 3;    // k_ = 0..63
  int bhHi = k_ >> 5;                  // 0 or 1
  int r_ = k_ & 31;                    // 0..31
  int bh = xcd + 8 * bhHi;             // b*8 + h
  int q0 = r_ * 64;
  int b = bh >> 3, h = bh & 7;

  // Q B-fragments (persistent): lane holds col q = f*16+cl, d-slice kk*32+g*8..+7
  u16x8 qf[4][2];
  {
    const u16* Qb = Q + ((size_t)(b * NQ + q0 + cl)) * D_ + h * HD + g * 8;
#pragma unroll
    for (int f = 0; f < 4; ++f)
#pragma unroll
      for (int kk = 0; kk < 2; ++kk)
        qf[f][kk] = *(const u16x8*)(Qb + (size_t)f * 16 * D_ + kk * 32);
  }

  // Loop-carried fragment pointers (static indices only — no scratch).
  const u16* kptr[4];
  const u16* vptr[4];
#pragma unroll
  for (int kf_ = 0; kf_ < 4; ++kf_)
    kptr[kf_] = K + ((size_t)b * NKV + kf_ * 16 + cl) * D_ + h * HD + g * 8;
#pragma unroll
  for (int j = 0; j < 4; ++j)
    vptr[j] = VpT + (size_t)b * (D_ * NKV) + (size_t)(h * HD + j * 16 + cl) * NKV
                  + g * 8;

  f32x4 o[4][4] = {};
  float lsum[4] = { 0.f, 0.f, 0.f, 0.f };   // lane-private partial denominators

  const int NT = NKV / 64;   // 32

  for (int t = 0; t < NT; ++t) {
    // K A-fragments (imm offsets 0/64B fit the 13-bit field)
    u16x8 kf[4][2];
#pragma unroll
    for (int kf_ = 0; kf_ < 4; ++kf_)
#pragma unroll
      for (int kk = 0; kk < 2; ++kk)
        kf[kf_][kk] = *(const u16x8*)(kptr[kf_] + kk * 32);

    // S' = K * Q'^T : sa[kf][f][r] = S'[key=kf*16+g*4+r][q=f*16+cl]
    f32x4 sa[4][4] = {};
    __builtin_amdgcn_s_setprio(1);
#pragma unroll
    for (int kk = 0; kk < 2; ++kk)
#pragma unroll
      for (int kf_ = 0; kf_ < 4; ++kf_)
#pragma unroll
        for (int f = 0; f < 4; ++f)
          sa[kf_][f] = mfma16(kf[kf_][kk], qf[f][kk], sa[kf_][f]);
    __builtin_amdgcn_s_setprio(0);

    // V^T A-fragments: issue now; consumed after exp phase (long cover).
    u16x8 vf[4][2];
#pragma unroll
    for (int j = 0; j < 4; ++j)
#pragma unroll
      for (int kk = 0; kk < 2; ++kk)
        vf[j][kk] = *(const u16x8*)(vptr[j] + kk * 32);

    // Fixed-max softmax: P = exp2(S') via single v_exp_f32 per element.
#pragma unroll
    for (int f = 0; f < 4; ++f) {
      float ps = 0.f;
#pragma unroll
      for (int kf_ = 0; kf_ < 4; ++kf_)
#pragma unroll
        for (int r = 0; r < 4; ++r) {
          float p = exp2fast(sa[kf_][f][r]);
          sa[kf_][f][r] = p;
          ps += p;
        }
      lsum[f] += ps;
    }

    // P -> LDS [q_local][key]: packed b32 writes (4B-aligned always)
#pragma unroll
    for (int f = 0; f < 4; ++f)
#pragma unroll
      for (int kf_ = 0; kf_ < 4; ++kf_) {
        unsigned lo = cvtpk(sa[kf_][f][0], sa[kf_][f][1]);
        unsigned hi = cvtpk(sa[kf_][f][2], sa[kf_][f][3]);
        unsigned* P32 = (unsigned*)&sm.p[f * 16 + cl][kf_ * 16 + g * 4];
        P32[0] = lo;
        P32[1] = hi;
      }

    // O^T += V^T * P^T (same-wave DS write->read is ordered; no barrier).
#pragma unroll
    for (int kk = 0; kk < 2; ++kk) {
      __builtin_amdgcn_s_setprio(1);
#pragma unroll
      for (int f = 0; f < 4; ++f) {
        u16x8 pa = *(const u16x8*)&sm.p[f * 16 + cl][kk * 32 + g * 8];
#pragma unroll
        for (int j = 0; j < 4; ++j)
          o[f][j] = mfma16(vf[j][kk], pa, o[f][j]);
      }
      __builtin_amdgcn_s_setprio(0);
    }

    // Advance loop-carried pointers (constant strides).
#pragma unroll
    for (int kf_ = 0; kf_ < 4; ++kf_) kptr[kf_] += 64 * D_;
#pragma unroll
    for (int j = 0; j < 4; ++j) vptr[j] += 64;
  }

  // Merge lane-private denominators across the 4 key-quarter partners (once),
  // then NORMALIZE in-register — no split merge needed.
  float inv[4];
#pragma unroll
  for (int f = 0; f < 4; ++f) {
    lsum[f] += __shfl_xor(lsum[f], 16, 64);
    lsum[f] += __shfl_xor(lsum[f], 32, 64);
    inv[f] = 1.f / lsum[f];
  }

  // Epilogue: store NORMALIZED O^T transposed via LDS, coalesced 16B stores.
#pragma unroll
  for (int f = 0; f < 4; ++f)
#pragma unroll
    for (int j = 0; j < 4; ++j) {
      int row = f * 16 + cl;
      sm.t[row][j * 8 + g * 2 + 0] = cvtpk(o[f][j][0] * inv[f], o[f][j][1] * inv[f]);
      sm.t[row][j * 8 + g * 2 + 1] = cvtpk(o[f][j][2] * inv[f], o[f][j][3] * inv[f]);
    }
  __syncthreads();  // single-wave barrier; orders LDS for readout
  {
    // One thread per q-row; 8 contiguous 16B stores each.
    int row = lane;
    u16* op = octx + (size_t)bh * NQ * HD + (size_t)(q0 + row) * HD;
#pragma unroll
    for (int i = 0; i < 8; ++i) {
      uint4 v;
      v.x = sm.t[row][i * 4 + 0];
      v.y = sm.t[row][i * 4 + 1];
      v.z = sm.t[row][i * 4 + 2];
      v.w = sm.t[row][i * 4 + 3];
      *(uint4*)(op + i * 8) = v;
    }
  }
}

// ---------------------------------------------------------------------------
// Kernel 4: residual + LayerNorm (no merge — attn output is normalized).
// 4 rows per 256-thread block (r15-verified structure).
// ---------------------------------------------------------------------------
__global__ __launch_bounds__(256) void resid_ln_kernel(
    const float* __restrict__ query, const u16* __restrict__ octx,
    const float* __restrict__ gamma, const float* __restrict__ beta,
    float* __restrict__ out) {
  int row = blockIdx.x * 4 + (threadIdx.x >> 6);   // b*NQ + q
  int lane = threadIdx.x & 63;
  int b = row >> 11, q = row & (NQ - 1);
  int h = lane >> 3;

  size_t base = (size_t)row * D_;
  const float4* q4 = (const float4*)(query + base);
  float4 a0 = q4[lane * 2], a1 = q4[lane * 2 + 1];
  float x[8] = { a0.x, a0.y, a0.z, a0.w, a1.x, a1.y, a1.z, a1.w };

  {
    size_t oi = ((size_t)(b * H_ + h) * NQ + q) * HD + (lane & 7) * 8;
    u16x8 ov = *(const u16x8*)(octx + oi);
#pragma unroll
    for (int e = 0; e < 8; ++e) x[e] += bf2f(ov[e]);
  }

  float sum = 0.f, sq = 0.f;
#pragma unroll
  for (int e = 0; e < 8; ++e) { sum += x[e]; sq += x[e] * x[e]; }
#pragma unroll
  for (int d = 1; d < 64; d <<= 1) {
    sum += __shfl_xor(sum, d, 64);
    sq  += __shfl_xor(sq,  d, 64);
  }
  float mean = sum * (1.f / D_);
  float var  = sq * (1.f / D_) - mean * mean;
  float rstd = rsqrtf(var + 1e-5f);

  const float4* g4  = (const float4*)gamma;
  const float4* be4 = (const float4*)beta;
  float4 g0 = g4[lane * 2], g1 = g4[lane * 2 + 1];
  float4 e0 = be4[lane * 2], e1 = be4[lane * 2 + 1];
  float4 o0, o1;
  o0.x = (x[0] - mean) * rstd * g0.x + e0.x;
  o0.y = (x[1] - mean) * rstd * g0.y + e0.y;
  o0.z = (x[2] - mean) * rstd * g0.z + e0.z;
  o0.w = (x[3] - mean) * rstd * g0.w + e0.w;
  o1.x = (x[4] - mean) * rstd * g1.x + e1.x;
  o1.y = (x[5] - mean) * rstd * g1.y + e1.y;
  o1.z = (x[6] - mean) * rstd * g1.z + e1.z;
  o1.w = (x[7] - mean) * rstd * g1.w + e1.w;
  ((float4*)(out + base))[lane * 2]     = o0;
  ((float4*)(out + base))[lane * 2 + 1] = o1;
}

// ---------------------------------------------------------------------------
// Workspace layout (bytes):
//   0          Qp    : Q proj bf16        4 MB
//   4194304    Kp    : K proj bf16        4 MB
//   8388608    VpT   : V proj transposed  4 MB
//   12582912   octx  : normalized ctx     4 MB (overlays qb; dead after gemm)
//   overlays (pre-attention only): qb@12582912, kvb@16777216, w*t@20971520
// ---------------------------------------------------------------------------
extern "C" void kernel_launch(void* const* d_in, const int* in_sizes, int n_in,
                              void* d_out, int out_size, void* d_ws, size_t ws_size,
                              hipStream_t stream) {
  const float* query     = (const float*)d_in[0];
  const float* key_value = (const float*)d_in[1];
  const float* Wq = (const float*)d_in[2];
  const float* bq = (const float*)d_in[3];
  const float* Wk = (const float*)d_in[4];
  const float* bk = (const float*)d_in[5];
  const float* Wv = (const float*)d_in[6];
  const float* bv = (const float*)d_in[7];
  const float* gamma = (const float*)d_in[8];
  const float* beta  = (const float*)d_in[9];
  float* out = (float*)d_out;

  char* ws = (char*)d_ws;
  u16* Qp    = (u16*)(ws + 0);
  u16* Kp    = (u16*)(ws + 4194304);
  u16* VpT   = (u16*)(ws + 8388608);
  u16* octx  = (u16*)(ws + 12582912);
  u16* qb    = (u16*)(ws + 12582912);   // overlay, dead after gemm_qkv
  u16* kvb   = (u16*)(ws + 16777216);
  u16* wqt   = (u16*)(ws + 20971520);
  u16* wkt   = (u16*)(ws + 21495808);
  u16* wvt   = (u16*)(ws + 22020096);

  prep_kernel<<<2816, 256, 0, stream>>>(query, key_value, Wq, Wk, Wv,
                                        qb, kvb, wqt, wkt, wvt);
  dim3 gg(MROWS / 64, 24);
  gemm_qkv<<<gg, 64, 0, stream>>>(qb, kvb, wqt, wkt, wvt, bq, bk, bv,
                                  Qp, Kp, VpT);
  attn_kernel<<<512, 64, 0, stream>>>(Qp, Kp, VpT, octx);
  resid_ln_kernel<<<MROWS / 4, 256, 0, stream>>>(query, octx, gamma, beta, out);
}

// Round 25
// 82.649 us; speedup vs baseline: 1.2030x; 1.2030x over previous
//
#include <hip/hip_runtime.h>
#include <stdint.h>

// Problem constants
#define B_     2
#define NQ     2048
#define NKV    2048
#define D_     512
#define H_     8
#define HD     64
#define MROWS  4096   // B_*NQ == B_*NKV
#define NSPLIT 2
#define SKEYS  (NKV / NSPLIT)   // 1024 keys per split

typedef unsigned short u16;
typedef __attribute__((ext_vector_type(4))) unsigned short u16x4;
typedef __attribute__((ext_vector_type(8))) unsigned short u16x8;
typedef __attribute__((ext_vector_type(8))) __bf16 bf16x8;
typedef __attribute__((ext_vector_type(4))) float f32x4;

__device__ __forceinline__ u16 f2bf(float f) {
  union { float f; unsigned int u; } v; v.f = f;
  unsigned int u = v.u;
  unsigned int r = (u + 0x7FFFu + ((u >> 16) & 1u)) >> 16;  // RNE
  return (u16)r;
}
__device__ __forceinline__ float bf2f(u16 b) {
  union { unsigned int u; float f; } v; v.u = ((unsigned int)b) << 16;
  return v.f;
}
__device__ __forceinline__ unsigned cvtpk(float a, float b) {  // low=bf(a), high=bf(b)
  unsigned r;
  asm("v_cvt_pk_bf16_f32 %0, %1, %2" : "=v"(r) : "v"(a), "v"(b));
  return r;
}
// Raw v_exp_f32 (2^x), single instruction (verified r21: halves VALUBusy).
__device__ __forceinline__ float exp2fast(float x) {
  return __builtin_amdgcn_exp2f(x);
}

__device__ __forceinline__ f32x4 mfma16(u16x8 a, u16x8 b, f32x4 c) {
  return __builtin_amdgcn_mfma_f32_16x16x32_bf16(
      __builtin_bit_cast(bf16x8, a), __builtin_bit_cast(bf16x8, b), c, 0, 0, 0);
}

// log2(e)/sqrt(HD): folded into the Q projection so exp2 applies directly.
#define QSCL 0.18033688011112042f

// ---------------------------------------------------------------------------
// Kernel 1: fused input prep (round-16/17 verified verbatim).
// ---------------------------------------------------------------------------
__global__ __launch_bounds__(256) void prep_kernel(
    const float* __restrict__ q, const float* __restrict__ kv,
    const float* __restrict__ Wq, const float* __restrict__ Wk,
    const float* __restrict__ Wv,
    u16* __restrict__ qb, u16* __restrict__ kvb,
    u16* __restrict__ wqt, u16* __restrict__ wkt, u16* __restrict__ wvt) {
  __shared__ float tile[32][33];
  int bx = blockIdx.x;
  if (bx < 2048) {
    int i = bx * 256 + threadIdx.x;   // 524288 exact
    float4 a = ((const float4*)q)[i];
    float4 b = ((const float4*)kv)[i];
    u16x4 ua = { f2bf(a.x), f2bf(a.y), f2bf(a.z), f2bf(a.w) };
    u16x4 ub = { f2bf(b.x), f2bf(b.y), f2bf(b.z), f2bf(b.w) };
    ((u16x4*)qb)[i]  = ua;
    ((u16x4*)kvb)[i] = ub;
  } else {
    int t = bx - 2048;                 // 0..767
    int which = t >> 8;
    t &= 255;
    int tr = t >> 4, tc = t & 15;      // tile row (k), tile col (n) in W
    const float* W = (which == 0) ? Wq : (which == 1) ? Wk : Wv;
    u16* WT = (which == 0) ? wqt : (which == 1) ? wkt : wvt;

    int tx = threadIdx.x & 31, ty = threadIdx.x >> 5;  // ty 0..7
#pragma unroll
    for (int i = 0; i < 4; ++i)
      tile[ty + 8 * i][tx] = W[(size_t)(tr * 32 + ty + 8 * i) * D_ + tc * 32 + tx];
    __syncthreads();
#pragma unroll
    for (int i = 0; i < 4; ++i)
      WT[(size_t)(tc * 32 + ty + 8 * i) * D_ + tr * 32 + tx] =
          f2bf(tile[tx][ty + 8 * i]);
  }
}

// ---------------------------------------------------------------------------
// Kernel 2: fused QKV GEMM (round-16 verified verbatim — best measured).
// ---------------------------------------------------------------------------
__global__ __launch_bounds__(64) void gemm_qkv(
    const u16* __restrict__ qb, const u16* __restrict__ kvb,
    const u16* __restrict__ wqt, const u16* __restrict__ wkt,
    const u16* __restrict__ wvt,
    const float* __restrict__ bq, const float* __restrict__ bk,
    const float* __restrict__ bv,
    u16* __restrict__ Qp, u16* __restrict__ Kp, u16* __restrict__ VpT) {
  __shared__ __align__(16) u16 tile[64][72];   // +8 pad -> 16B-aligned rows

  int lane = threadIdx.x;
  int cl = lane & 15, g = lane >> 4;
  int y = blockIdx.y;
  int which = y >> 3;
  int col0 = (y & 7) * 64;
  int row0 = blockIdx.x * 64;

  const u16* A   = (which == 0) ? qb : kvb;
  const u16* WT  = (which == 0) ? wqt : (which == 1) ? wkt : wvt;
  const float* bias = (which == 0) ? bq : (which == 1) ? bk : bv;
  u16* Out = (which == 0) ? Qp : (which == 1) ? Kp : VpT;
  float oscale = (which == 0) ? QSCL : 1.0f;

  const u16* Abase = A  + (size_t)(row0 + cl) * D_ + g * 8;
  const u16* Bbase = WT + (size_t)(col0 + cl) * D_ + g * 8;

  f32x4 acc[4][4] = {};
  u16x8 afA[4], bfA[4], afB[4], bfB[4];
#pragma unroll
  for (int i = 0; i < 4; ++i) afA[i] = *(const u16x8*)(Abase + (size_t)i * 16 * D_);
#pragma unroll
  for (int j = 0; j < 4; ++j) bfA[j] = *(const u16x8*)(Bbase + (size_t)j * 16 * D_);

#pragma unroll
  for (int kk = 0; kk < 16; ++kk) {
    const u16x8* ca = (kk & 1) ? afB : afA;
    const u16x8* cw = (kk & 1) ? bfB : bfA;
    u16x8* na = (kk & 1) ? afA : afB;
    u16x8* nw = (kk & 1) ? bfA : bfB;
    if (kk < 15) {                        // static guard (unrolled) — no spill
      int k0 = kk * 32 + 32;
#pragma unroll
      for (int i = 0; i < 4; ++i) na[i] = *(const u16x8*)(Abase + (size_t)i * 16 * D_ + k0);
#pragma unroll
      for (int j = 0; j < 4; ++j) nw[j] = *(const u16x8*)(Bbase + (size_t)j * 16 * D_ + k0);
    }
    __builtin_amdgcn_s_setprio(1);
#pragma unroll
    for (int i = 0; i < 4; ++i)
#pragma unroll
      for (int j = 0; j < 4; ++j)
        acc[i][j] = mfma16(ca[i], cw[j], acc[i][j]);
    __builtin_amdgcn_s_setprio(0);
  }

  // Epilogue: bias + scale -> LDS tile -> coalesced 16B stores.
#pragma unroll
  for (int j = 0; j < 4; ++j) {
    float bv2 = bias[col0 + j * 16 + cl];
#pragma unroll
    for (int i = 0; i < 4; ++i)
#pragma unroll
      for (int r = 0; r < 4; ++r) {
        u16 val = f2bf((acc[i][j][r] + bv2) * oscale);
        int rr = i * 16 + g * 4 + r, cc = j * 16 + cl;
        if (which != 2) tile[rr][cc] = val;
        else            tile[cc][rr] = val;
      }
  }
  u16* dst;
  if (which != 2) {
    dst = Out + (size_t)(row0 + lane) * D_ + col0;
  } else {
    int b_ = row0 >> 11, key0 = row0 & (NKV - 1);
    dst = Out + (size_t)b_ * (D_ * NKV) + (size_t)(col0 + lane) * NKV + key0;
  }
#pragma unroll
  for (int c8 = 0; c8 < 8; ++c8) {
    uint4 v = *(const uint4*)&tile[lane][c8 * 8];
    *(uint4*)(dst + c8 * 8) = v;
  }
}

// ---------------------------------------------------------------------------
// Kernel 3: split-KV flash attention (round-23 verified verbatim: 1 wave /
// block, 64 q-rows, swapped QK^T, fixed-max exp2fast softmax, pointer-
// carried K/V fragments, XCD-affinity grid, NSPLIT=2).
// ---------------------------------------------------------------------------
__global__ __launch_bounds__(64, 2) void attn_kernel(
    const u16* __restrict__ Q, const u16* __restrict__ K,
    const u16* __restrict__ VpT, u16* __restrict__ opart,
    float* __restrict__ ml) {
  __shared__ union __align__(16) {
    u16 p[64][66];       // P: [q_local][key], stride 132B (round-2 pattern)
    unsigned t[64][33];  // epilogue O transpose (same 132B row stride)
  } sm;

  int lane = threadIdx.x;              // one wave
  int cl = lane & 15, g = lane >> 4;

  // XCD-affinity decode: 1024 blocks; per bh: 32 q-tiles x 2 splits = 64.
  int lin = blockIdx.x;                // 0..1023
  int xcd = lin & 7, k_ = lin >> 3;    // k_ = 0..127
  int bhHi = k_ >> 6;                  // 0 or 1
  int r_ = k_ & 63;                    // 0..63
  int bh = xcd + 8 * bhHi;             // b*8 + h
  int q0 = (r_ >> 1) * 64;
  int s  = r_ & 1;                     // KV split
  int b = bh >> 3, h = bh & 7;

  // Q B-fragments (persistent): lane holds col q = f*16+cl, d-slice kk*32+g*8..+7
  u16x8 qf[4][2];
  {
    const u16* Qb = Q + ((size_t)(b * NQ + q0 + cl)) * D_ + h * HD + g * 8;
#pragma unroll
    for (int f = 0; f < 4; ++f)
#pragma unroll
      for (int kk = 0; kk < 2; ++kk)
        qf[f][kk] = *(const u16x8*)(Qb + (size_t)f * 16 * D_ + kk * 32);
  }

  // Loop-carried fragment pointers (static indices only — no scratch).
  const u16* kptr[4];
  const u16* vptr[4];
#pragma unroll
  for (int kf_ = 0; kf_ < 4; ++kf_)
    kptr[kf_] = K + ((size_t)b * NKV + s * SKEYS + kf_ * 16 + cl) * D_ + h * HD + g * 8;
#pragma unroll
  for (int j = 0; j < 4; ++j)
    vptr[j] = VpT + (size_t)b * (D_ * NKV) + (size_t)(h * HD + j * 16 + cl) * NKV
                  + s * SKEYS + g * 8;

  f32x4 o[4][4] = {};
  float lsum[4] = { 0.f, 0.f, 0.f, 0.f };   // lane-private partial denominators

  const int NT = SKEYS / 64;   // 16

  for (int t = 0; t < NT; ++t) {
    // K A-fragments (imm offsets 0/64B fit the 13-bit field)
    u16x8 kf[4][2];
#pragma unroll
    for (int kf_ = 0; kf_ < 4; ++kf_)
#pragma unroll
      for (int kk = 0; kk < 2; ++kk)
        kf[kf_][kk] = *(const u16x8*)(kptr[kf_] + kk * 32);

    // S' = K * Q'^T : sa[kf][f][r] = S'[key=kf*16+g*4+r][q=f*16+cl]
    f32x4 sa[4][4] = {};
    __builtin_amdgcn_s_setprio(1);
#pragma unroll
    for (int kk = 0; kk < 2; ++kk)
#pragma unroll
      for (int kf_ = 0; kf_ < 4; ++kf_)
#pragma unroll
        for (int f = 0; f < 4; ++f)
          sa[kf_][f] = mfma16(kf[kf_][kk], qf[f][kk], sa[kf_][f]);
    __builtin_amdgcn_s_setprio(0);

    // V^T A-fragments: issue now; consumed after exp phase (long cover).
    u16x8 vf[4][2];
#pragma unroll
    for (int j = 0; j < 4; ++j)
#pragma unroll
      for (int kk = 0; kk < 2; ++kk)
        vf[j][kk] = *(const u16x8*)(vptr[j] + kk * 32);

    // Fixed-max softmax: P = exp2(S') via single v_exp_f32 per element.
#pragma unroll
    for (int f = 0; f < 4; ++f) {
      float ps = 0.f;
#pragma unroll
      for (int kf_ = 0; kf_ < 4; ++kf_)
#pragma unroll
        for (int r = 0; r < 4; ++r) {
          float p = exp2fast(sa[kf_][f][r]);
          sa[kf_][f][r] = p;
          ps += p;
        }
      lsum[f] += ps;
    }

    // P -> LDS [q_local][key]: packed b32 writes (4B-aligned always)
#pragma unroll
    for (int f = 0; f < 4; ++f)
#pragma unroll
      for (int kf_ = 0; kf_ < 4; ++kf_) {
        unsigned lo = cvtpk(sa[kf_][f][0], sa[kf_][f][1]);
        unsigned hi = cvtpk(sa[kf_][f][2], sa[kf_][f][3]);
        unsigned* P32 = (unsigned*)&sm.p[f * 16 + cl][kf_ * 16 + g * 4];
        P32[0] = lo;
        P32[1] = hi;
      }

    // O^T += V^T * P^T (same-wave DS write->read is ordered; no barrier).
#pragma unroll
    for (int kk = 0; kk < 2; ++kk) {
      __builtin_amdgcn_s_setprio(1);
#pragma unroll
      for (int f = 0; f < 4; ++f) {
        u16x8 pa = *(const u16x8*)&sm.p[f * 16 + cl][kk * 32 + g * 8];
#pragma unroll
        for (int j = 0; j < 4; ++j)
          o[f][j] = mfma16(vf[j][kk], pa, o[f][j]);
      }
      __builtin_amdgcn_s_setprio(0);
    }

    // Advance loop-carried pointers (constant strides).
#pragma unroll
    for (int kf_ = 0; kf_ < 4; ++kf_) kptr[kf_] += 64 * D_;
#pragma unroll
    for (int j = 0; j < 4; ++j) vptr[j] += 64;
  }

  // Merge lane-private denominators across the 4 key-quarter partners (once).
#pragma unroll
  for (int f = 0; f < 4; ++f) {
    lsum[f] += __shfl_xor(lsum[f], 16, 64);
    lsum[f] += __shfl_xor(lsum[f], 32, 64);
  }

  // Epilogue: store UNNORMALIZED O^T transposed via LDS, coalesced 16B stores.
#pragma unroll
  for (int f = 0; f < 4; ++f)
#pragma unroll
    for (int j = 0; j < 4; ++j) {
      int row = f * 16 + cl;
      sm.t[row][j * 8 + g * 2 + 0] = cvtpk(o[f][j][0], o[f][j][1]);
      sm.t[row][j * 8 + g * 2 + 1] = cvtpk(o[f][j][2], o[f][j][3]);
    }
  if (g == 0) {
#pragma unroll
    for (int f = 0; f < 4; ++f) {
      size_t mi = ((size_t)(bh * NSPLIT + s) * NQ + q0 + f * 16 + cl) * 2;
      ml[mi]     = 0.f;        // fixed max (log2 domain)
      ml[mi + 1] = lsum[f];
    }
  }
  __syncthreads();  // single-wave barrier; orders LDS for readout
  {
    // One thread per q-row; 8 contiguous 16B stores each.
    int row = lane;
    u16* op = opart + (size_t)(bh * NSPLIT + s) * NQ * HD + (size_t)(q0 + row) * HD;
#pragma unroll
    for (int i = 0; i < 8; ++i) {
      uint4 v;
      v.x = sm.t[row][i * 4 + 0];
      v.y = sm.t[row][i * 4 + 1];
      v.z = sm.t[row][i * 4 + 2];
      v.w = sm.t[row][i * 4 + 3];
      *(uint4*)(op + i * 8) = v;
    }
  }
}

// ---------------------------------------------------------------------------
// Kernel 4: combine split-KV partials + residual + LayerNorm, fused.
// (round-23 verified verbatim at NS=2; expects UNNORMALIZED opart, ms == 0)
// ---------------------------------------------------------------------------
__global__ __launch_bounds__(256) void combine_ln_kernel(
    const float* __restrict__ query, const u16* __restrict__ opart,
    const float* __restrict__ ml,
    const float* __restrict__ gamma, const float* __restrict__ beta,
    float* __restrict__ out) {
  int row = blockIdx.x * 4 + (threadIdx.x >> 6);   // b*NQ + q
  int lane = threadIdx.x & 63;
  int b = row >> 11, q = row & (NQ - 1);
  int h = lane >> 3;

  float ms[NSPLIT], ls[NSPLIT];
  float mmax = -1e30f;
#pragma unroll
  for (int s = 0; s < NSPLIT; ++s) {
    size_t mi = ((size_t)((b * H_ + h) * NSPLIT + s) * NQ + q) * 2;
    ms[s] = ml[mi];
    ls[s] = ml[mi + 1];
    mmax = fmaxf(mmax, ms[s]);
  }
  float lt = 0.f;
#pragma unroll
  for (int s = 0; s < NSPLIT; ++s) lt += ls[s] * exp2fast(ms[s] - mmax);
  float inv = 1.f / lt;

  size_t base = (size_t)row * D_;
  const float4* q4 = (const float4*)(query + base);
  float4 a0 = q4[lane * 2], a1 = q4[lane * 2 + 1];
  float x[8] = { a0.x, a0.y, a0.z, a0.w, a1.x, a1.y, a1.z, a1.w };

#pragma unroll
  for (int s = 0; s < NSPLIT; ++s) {
    size_t oi = ((size_t)((b * H_ + h) * NSPLIT + s) * NQ + q) * HD + (lane & 7) * 8;
    u16x8 ov = *(const u16x8*)(opart + oi);
    float sc = exp2fast(ms[s] - mmax) * inv;
#pragma unroll
    for (int e = 0; e < 8; ++e) x[e] += bf2f(ov[e]) * sc;
  }

  float sum = 0.f, sq = 0.f;
#pragma unroll
  for (int e = 0; e < 8; ++e) { sum += x[e]; sq += x[e] * x[e]; }
#pragma unroll
  for (int d = 1; d < 64; d <<= 1) {
    sum += __shfl_xor(sum, d, 64);
    sq  += __shfl_xor(sq,  d, 64);
  }
  float mean = sum * (1.f / D_);
  float var  = sq * (1.f / D_) - mean * mean;
  float rstd = rsqrtf(var + 1e-5f);

  const float4* g4  = (const float4*)gamma;
  const float4* be4 = (const float4*)beta;
  float4 g0 = g4[lane * 2], g1 = g4[lane * 2 + 1];
  float4 e0 = be4[lane * 2], e1 = be4[lane * 2 + 1];
  float4 o0, o1;
  o0.x = (x[0] - mean) * rstd * g0.x + e0.x;
  o0.y = (x[1] - mean) * rstd * g0.y + e0.y;
  o0.z = (x[2] - mean) * rstd * g0.z + e0.z;
  o0.w = (x[3] - mean) * rstd * g0.w + e0.w;
  o1.x = (x[4] - mean) * rstd * g1.x + e1.x;
  o1.y = (x[5] - mean) * rstd * g1.y + e1.y;
  o1.z = (x[6] - mean) * rstd * g1.z + e1.z;
  o1.w = (x[7] - mean) * rstd * g1.w + e1.w;
  ((float4*)(out + base))[lane * 2]     = o0;
  ((float4*)(out + base))[lane * 2 + 1] = o1;
}

// ---------------------------------------------------------------------------
// Workspace layout (bytes):
//   0          Qp    : Q proj bf16        4 MB
//   4194304    Kp    : K proj bf16        4 MB
//   8388608    VpT   : V proj transposed  4 MB
//   12582912   opart : bf16 partial O     8 MB (NS=2; overlays qb/kvb)
//   29360128   ml    : f32 (m,l)          0.5 MB
//   overlays (pre-attention only): qb@12582912, kvb@16777216, w*t@20971520
//   opart (8 MB) ends at 20971520 — does not touch the weight overlays.
// ---------------------------------------------------------------------------
extern "C" void kernel_launch(void* const* d_in, const int* in_sizes, int n_in,
                              void* d_out, int out_size, void* d_ws, size_t ws_size,
                              hipStream_t stream) {
  const float* query     = (const float*)d_in[0];
  const float* key_value = (const float*)d_in[1];
  const float* Wq = (const float*)d_in[2];
  const float* bq = (const float*)d_in[3];
  const float* Wk = (const float*)d_in[4];
  const float* bk = (const float*)d_in[5];
  const float* Wv = (const float*)d_in[6];
  const float* bv = (const float*)d_in[7];
  const float* gamma = (const float*)d_in[8];
  const float* beta  = (const float*)d_in[9];
  float* out = (float*)d_out;

  char* ws = (char*)d_ws;
  u16* Qp    = (u16*)(ws + 0);
  u16* Kp    = (u16*)(ws + 4194304);
  u16* VpT   = (u16*)(ws + 8388608);
  u16* opart = (u16*)(ws + 12582912);
  float* ml  = (float*)(ws + 29360128);
  u16* qb    = (u16*)(ws + 12582912);   // overlay, dead after gemm_qkv
  u16* kvb   = (u16*)(ws + 16777216);
  u16* wqt   = (u16*)(ws + 20971520);
  u16* wkt   = (u16*)(ws + 21495808);
  u16* wvt   = (u16*)(ws + 22020096);

  prep_kernel<<<2816, 256, 0, stream>>>(query, key_value, Wq, Wk, Wv,
                                        qb, kvb, wqt, wkt, wvt);
  dim3 gg(MROWS / 64, 24);
  gemm_qkv<<<gg, 64, 0, stream>>>(qb, kvb, wqt, wkt, wvt, bq, bk, bv,
                                  Qp, Kp, VpT);
  attn_kernel<<<1024, 64, 0, stream>>>(Qp, Kp, VpT, opart, ml);
  combine_ln_kernel<<<MROWS / 4, 256, 0, stream>>>(query, opart, ml, gamma, beta, out);
}